// Round 1
// baseline (577.235 us; speedup 1.0000x reference)
//
#include <hip/hip_runtime.h>

// Problem constants (from reference):
//   N = 512, DX = 1/511, DT = 1e-7, NUM_STEPS = 200 -> 199 output states
//   MB = 256 (material boundary column), interface column ii = 255
#define GN 512
#define GNN (GN * GN)
#define NSTEPS 199

// Temporal fusion parameters:
//   TS = output tile edge (32), KS = fused steps per launch (10)
//   HS = held tile edge = TS + 2*KS (halo ring per fused step)
// Clean-region induction: after s fused steps the correct local region is
// [s, HS-1-s]^2 which contains the owned [KS, KS+TS-1]^2 for all s <= KS.
#define TS 32
#define KS 10
#define HS (TS + 2 * KS)   // 52
#define CR (HS - 2)        // computed region edge per step: local [1, HS-2]
#define BTH 512            // 8 waves/block, 1 block/CU at grid=256

// Precomputed coefficients (double -> float once):
//   c_diff = DT / DX^2 = 1e-7 * 511^2
//   c_adv  = DT / (2*DX) = 1e-7 * 511 / 2
//   c_rea  = DT
__constant__ const float kCdiff = (float)(1e-7 * 511.0 * 511.0); // 0.0261121
__constant__ const float kCadv  = (float)(1e-7 * 511.0 / 2.0);   // 2.5555e-5
__constant__ const float kCrea  = 1e-7f;

// Fused multi-step kernel. Per-point closed form (verified in the 670us
// single-step kernel against the reference op order):
//   out(i,j) = inner(clamp(i,1,510), clamp(j,1,510))
// where inner(ic,jc) on the OLD state T is:
//   jc==255 : (k1*T[ic,256] + k2*T[ic,254]) / (k1+k2)
//   else    : Tc - DT*kap*(Tc^2*Tx - Tc*Ty) + DT*alp*(Txx+Tyy)
//             + DT*kap*(Tc^3 - Tc^2 + Tc)
//   kap/alp = (jc<256) ? k1/alpha1 : k2/alpha2
// Each block owns output tile [r0,r0+TS) x [c0,c0+TS); holds
// [r0-KS, r0+TS+KS) x [c0-KS, c0+TS+KS) in LDS (loaded with clamped global
// indices so every cell is initialized), advances nsteps steps, and stores
// its owned region to the per-step output slice.
__global__ __launch_bounds__(BTH) void adr_multi(
    const float* __restrict__ src, float* __restrict__ dstbase, int nsteps,
    const float* __restrict__ pk1, const float* __restrict__ pk2,
    const float* __restrict__ pa1, const float* __restrict__ pa2)
{
    __shared__ float buf[2][HS][HS];

    const int tid = threadIdx.x;
    const int bx = blockIdx.x & 15;   // tile col
    const int by = blockIdx.x >> 4;   // tile row
    const int r0 = by * TS;
    const int c0 = bx * TS;
    const int rb = r0 - KS;           // held-region base (may be negative)
    const int cb = c0 - KS;

    const float k1 = pk1[0];
    const float k2 = pk2[0];
    const float a1 = pa1[0];
    const float a2 = pa2[0];

    // Load held region, clamped at domain edges (all cells initialized).
    for (int idx = tid; idx < HS * HS; idx += BTH) {
        const int h = idx / HS;
        const int c = idx - h * HS;
        const int gr = min(max(rb + h, 0), GN - 1);
        const int gc = min(max(cb + c, 0), GN - 1);
        buf[0][h][c] = src[gr * GN + gc];
    }
    __syncthreads();

    int cur = 0;
    for (int s = 0; s < nsteps; ++s) {
        float* __restrict__ dst = dstbase + (size_t)s * GNN;
        const int nxt = cur ^ 1;
        for (int idx = tid; idx < CR * CR; idx += BTH) {
            const int h = 1 + idx / CR;
            const int c = 1 + (idx - (h - 1) * CR);
            const int gr = rb + h;
            const int gc = cb + c;
            if ((unsigned)gr < GN && (unsigned)gc < GN) {
                const int ic = min(max(gr, 1), GN - 2);
                const int jc = min(max(gc, 1), GN - 2);
                const int lh = ic - rb;
                const int lc = jc - cb;
                const float tc = buf[cur][lh][lc];
                const float tl = buf[cur][lh][lc - 1];
                const float tr = buf[cur][lh][lc + 1];
                const float tm = buf[cur][lh - 1][lc];
                const float tp = buf[cur][lh + 1][lc];
                float out;
                if (jc == 255) {
                    // interface column (old state): k_left=k1, k_right=k2
                    out = (k1 * tr + k2 * tl) / (k1 + k2);
                } else {
                    const float kap = (jc < 256) ? k1 : k2;
                    const float alp = (jc < 256) ? a1 : a2;
                    const float adv = kap * kCadv *
                        (tc * tc * (tp - tm) - tc * (tr - tl));
                    const float dif = alp * kCdiff *
                        ((tm + tp + tl + tr) - 4.0f * tc);
                    const float rea = kCrea * kap *
                        ((tc * tc * tc - tc * tc) + tc);
                    out = tc - adv + dif + rea;
                }
                buf[nxt][h][c] = out;
                if ((unsigned)(gr - r0) < TS && (unsigned)(gc - c0) < TS)
                    dst[gr * GN + gc] = out;
            }
        }
        __syncthreads();
        cur = nxt;
    }
}

extern "C" void kernel_launch(void* const* d_in, const int* in_sizes, int n_in,
                              void* d_out, int out_size, void* d_ws, size_t ws_size,
                              hipStream_t stream) {
    (void)in_sizes; (void)n_in; (void)out_size; (void)d_ws; (void)ws_size;

    const float* u0 = (const float*)d_in[0];
    const float* k1 = (const float*)d_in[1];
    const float* k2 = (const float*)d_in[2];
    const float* a1 = (const float*)d_in[3];
    const float* a2 = (const float*)d_in[4];
    float* out = (float*)d_out;

    const dim3 block(BTH);
    const dim3 grid((GN / TS) * (GN / TS));   // 16x16 = 256 blocks

    const float* src = u0;
    int step = 0;
    while (step < NSTEPS) {
        const int ns = (NSTEPS - step < KS) ? (NSTEPS - step) : KS;
        float* dstbase = out + (size_t)step * GNN;
        adr_multi<<<grid, block, 0, stream>>>(src, dstbase, ns, k1, k2, a1, a2);
        src = dstbase + (size_t)(ns - 1) * GNN;
        step += ns;
    }
}

// Round 2
// 407.642 us; speedup vs baseline: 1.4160x; 1.4160x over previous
//
#include <hip/hip_runtime.h>

// Problem constants (from reference):
//   N = 512, DX = 1/511, DT = 1e-7, NUM_STEPS = 200 -> 199 output states
//   MB = 256 (material boundary column), interface column ii = 255
#define GN 512
#define GNN (GN * GN)
#define NSTEPS 199

// Register-resident temporal fusion:
//   TS = 32 output tile, KS = 16 fused steps, HS = TS + 2*KS = 64 held tile.
//   Block = 8 waves x 64 lanes. lane = local column (64 cols = wave width),
//   wave w holds rows [8w, 8w+8) of the held tile in registers (cur[8]).
//   Per step: exchange strip-edge rows via LDS (double-buffered, 1 barrier),
//   horizontal neighbors via __shfl(lane+-1), all state stays in VGPRs.
// Clean-region induction: after s steps rows/cols [s, 63-s] are correct;
// owned region [16,47]^2 is clean for all s <= 16. Physical-boundary tiles
// don't shrink at the boundary side because the boundary rule is applied
// locally each step (row/col copies below).
#define TS 32
#define KS 16
#define HS 64
#define WROWS 8
#define NW 8
#define BTH 512

// Precomputed coefficients (double -> float once):
//   c_diff = DT / DX^2 = 1e-7 * 511^2
//   c_adv  = DT / (2*DX) = 1e-7 * 511 / 2
//   c_rea  = DT
__constant__ const float kCdiff = (float)(1e-7 * 511.0 * 511.0); // 0.0261121
__constant__ const float kCadv  = (float)(1e-7 * 511.0 / 2.0);   // 2.5555e-5
__constant__ const float kCrea  = 1e-7f;

// Per-point closed form (verified against reference by the passing 577us
// kernel): out(i,j) = inner(clamp(i,1,510), clamp(j,1,510)), where
//   jc==255 : (k1*T[ic,256] + k2*T[ic,254]) / (k1+k2)        (old T)
//   else    : Tc - DT*kap*(Tc^2*(tp-tm)/... ) ... (adv/dif/rea below)
// kap/alp = (jc<256) ? k1/alpha1 : k2/alpha2.
// Boundary maintenance per step (order matters: rows, then cols):
//   state(0,:) = state(1,:); state(511,:) = state(510,:);
//   state(:,0) = state(:,1); state(:,511) = state(:,510).
// Cells strictly outside the domain halo are never read by valid cells.
__global__ __launch_bounds__(BTH) void adr_fused(
    const float* __restrict__ src, float* __restrict__ dstbase, int nsteps,
    const float* __restrict__ pk1, const float* __restrict__ pk2,
    const float* __restrict__ pa1, const float* __restrict__ pa2)
{
    // Strip-edge exchange buffers: [parity][top=0/bot=1][wave][lane]
    __shared__ float xg[2][2][NW][HS];

    const int lane = threadIdx.x & 63;
    const int w    = threadIdx.x >> 6;
    const int bx = blockIdx.x & 15;   // tile col
    const int by = blockIdx.x >> 4;   // tile row
    const int r0 = by * TS;
    const int c0 = bx * TS;
    const int rb = r0 - KS;           // held-region base row (may be <0)
    const int cb = c0 - KS;           // held-region base col
    const int gc  = cb + lane;        // this lane's global column
    const int gr0 = rb + w * WROWS;   // first global row of this wave's strip

    const float k1 = pk1[0];
    const float k2 = pk2[0];
    const float a1 = pa1[0];
    const float a2 = pa2[0];

    // Loop-invariant per-lane material constants.
    const float kap = (gc < 256) ? k1 : k2;
    const float alp = (gc < 256) ? a1 : a2;
    const bool  ifc = (gc == 255);
    const float inv12 = 1.0f / (k1 + k2);
    const float ckA = kap * kCadv;
    const float ckD = alp * kCdiff;
    const float ckR = kCrea * kap;

    // Loop-invariant shuffle sources (clamped: no UB, edge lanes self-read;
    // those lanes are either fixed by the column rule or never read).
    const int srcL = (lane == 0) ? 0 : lane - 1;
    const int srcR = (lane == HS - 1) ? HS - 1 : lane + 1;

    // Initial load: state(clamp(gr), clamp(gc)) — coalesced 256B per row.
    float cur[WROWS];
    const int gcc = min(max(gc, 0), GN - 1);
    #pragma unroll
    for (int k = 0; k < WROWS; ++k) {
        const int gr = min(max(gr0 + k, 0), GN - 1);
        cur[k] = src[gr * GN + gcc];
    }

    // Boundary-fix roles (uniform per block/wave).
    const bool fixTop = (by == 0)  && (w == 2); // local row 16 = global row 0
    const bool fixBot = (by == 15) && (w == 5); // local row 47 = global row 511
    const bool fixL   = (bx == 0);              // lane 16 = global col 0
    const bool fixR   = (bx == 15);             // lane 47 = global col 511
    const bool stores = (w >= 2 && w <= 5) && (lane >= 16 && lane < 48);

    int par = 0;
    for (int s = 0; s < nsteps; ++s) {
        // 1. publish old strip-edge rows (parity-double-buffered)
        xg[par][0][w][lane] = cur[0];
        xg[par][1][w][lane] = cur[WROWS - 1];
        __syncthreads();
        // 2. fetch neighbor-strip edge rows (self-read at block edge: halo-
        //    dirty rows, never consumed by valid cells)
        const float above = (w > 0)      ? xg[par][1][w - 1][lane] : cur[0];
        const float below = (w < NW - 1) ? xg[par][0][w + 1][lane] : cur[WROWS - 1];

        // 3. compute one time step, fully in registers
        float nxt[WROWS];
        #pragma unroll
        for (int k = 0; k < WROWS; ++k) {
            const float tc = cur[k];
            const float tm = (k == 0)         ? above : cur[k - 1];
            const float tp = (k == WROWS - 1) ? below : cur[k + 1];
            const float tl = __shfl(tc, srcL);
            const float tr = __shfl(tc, srcR);
            const float adv = ckA * (tc * tc * (tp - tm) - tc * (tr - tl));
            const float dif = ckD * ((tm + tp + tl + tr) - 4.0f * tc);
            const float rea = ckR * ((tc * tc * tc - tc * tc) + tc);
            float v = tc - adv + dif + rea;
            const float vif = (k1 * tr + k2 * tl) * inv12;
            nxt[k] = ifc ? vif : v;
        }

        // 4a. row boundary rule (before column rule, matching reference order)
        if (fixTop) nxt[0] = nxt[1];
        if (fixBot) nxt[WROWS - 1] = nxt[WROWS - 2];
        // 4b. column boundary rule: col 0 <- col 1 (lane 16 <- 17),
        //     col 511 <- col 510 (lane 47 <- 46); halo lanes get same copy.
        if (fixL) {
            #pragma unroll
            for (int k = 0; k < WROWS; ++k) {
                const float t = __shfl(nxt[k], 17);
                if (lane <= 16) nxt[k] = t;
            }
        }
        if (fixR) {
            #pragma unroll
            for (int k = 0; k < WROWS; ++k) {
                const float t = __shfl(nxt[k], 46);
                if (lane >= 47) nxt[k] = t;
            }
        }

        // 5. store owned 32x32 region for this step's output slice
        float* __restrict__ dst = dstbase + (size_t)s * GNN;
        if (stores) {
            #pragma unroll
            for (int k = 0; k < WROWS; ++k)
                dst[(gr0 + k) * GN + gc] = nxt[k];
        }

        // 6. advance
        #pragma unroll
        for (int k = 0; k < WROWS; ++k) cur[k] = nxt[k];
        par ^= 1;
        // no second barrier needed: next step writes the other parity buffer,
        // and the step-after-next's writes are ordered by the next barrier.
    }
}

extern "C" void kernel_launch(void* const* d_in, const int* in_sizes, int n_in,
                              void* d_out, int out_size, void* d_ws, size_t ws_size,
                              hipStream_t stream) {
    (void)in_sizes; (void)n_in; (void)out_size; (void)d_ws; (void)ws_size;

    const float* u0 = (const float*)d_in[0];
    const float* k1 = (const float*)d_in[1];
    const float* k2 = (const float*)d_in[2];
    const float* a1 = (const float*)d_in[3];
    const float* a2 = (const float*)d_in[4];
    float* out = (float*)d_out;

    const dim3 block(BTH);
    const dim3 grid((GN / TS) * (GN / TS));   // 16x16 = 256 blocks, 1/CU

    const float* src = u0;
    int step = 0;
    while (step < NSTEPS) {
        const int ns = (NSTEPS - step < KS) ? (NSTEPS - step) : KS;
        float* dstbase = out + (size_t)step * GNN;
        adr_fused<<<grid, block, 0, stream>>>(src, dstbase, ns, k1, k2, a1, a2);
        src = dstbase + (size_t)(ns - 1) * GNN;
        step += ns;
    }
}

// Round 3
// 391.796 us; speedup vs baseline: 1.4733x; 1.0404x over previous
//
#include <hip/hip_runtime.h>

// Problem constants (from reference):
//   N = 512, DX = 1/511, DT = 1e-7, NUM_STEPS = 200 -> 199 output states
//   MB = 256 (material boundary column), interface column ii = 255
#define GN 512
#define GNN (GN * GN)
#define NSTEPS 199

// Barrier-free register-resident temporal fusion:
//   TS = 16 output tile, KS = 8 fused steps, HS = 32 held tile.
//   ONE WAVE owns an entire held tile: lane grid 8x8, each lane holds a
//   4x4 cell patch in registers (cur[4][4]). Neighbor exchange = 16 shfls
//   per step (patch edges). No LDS, no __syncthreads, no inter-wave deps.
//   Grid = 32x32 = 1024 waves -> 4 waves/CU = 1/SIMD, all independent.
// Clean-region induction: after s steps local rows/cols [s, 31-s] are
// correct; owned region [8,23]^2 is clean for all s <= KS = 8. Boundary
// tiles stay clean at the boundary side because the boundary rule is
// applied locally each step (intra-lane copies below). Halo garbage is
// always finite (clamped loads / real neighbor data), so no NaN risk.
#define TS 16
#define KS 8
#define HS 32
#define PR 4   // patch rows per lane
#define PC 4   // patch cols per lane

// Precomputed coefficients (double -> float once):
__constant__ const float kCdiff = (float)(1e-7 * 511.0 * 511.0); // DT/DX^2
__constant__ const float kCadv  = (float)(1e-7 * 511.0 / 2.0);   // DT/(2DX)
__constant__ const float kCrea  = 1e-7f;                          // DT

// Per-point closed form (verified by the passing 577/407us kernels):
//   out(i,j) = inner(clamp(i,1,510), clamp(j,1,510)); inner on OLD T:
//   jc==255 : (k1*T[ic,256] + k2*T[ic,254]) / (k1+k2)
//   else    : Tc - kap*cA*(Tc^2*(tp-tm) - Tc*(tr-tl))
//             + alp*cD*(tm+tp+tl+tr-4Tc) + kap*cR*(Tc^3 - Tc^2 + Tc)
// Per-step boundary maintenance (rows before cols, matching reference):
//   row0<-row1, row511<-row510, col0<-col1, col511<-col510.
__global__ __launch_bounds__(64) void adr_fused(
    const float* __restrict__ src, float* __restrict__ dstbase, int nsteps,
    const float* __restrict__ pk1, const float* __restrict__ pk2,
    const float* __restrict__ pa1, const float* __restrict__ pa2)
{
    const int lane = threadIdx.x & 63;
    const int cg = lane & 7;        // col group (8 groups x 4 cols = 32)
    const int rg = lane >> 3;       // row group
    const int bx = blockIdx.x & 31; // tile col
    const int by = blockIdx.x >> 5; // tile row
    const int rb = by * TS - KS;    // held-region base row (may be <0)
    const int cb = bx * TS - KS;    // held-region base col
    const int pr0 = rb + rg * PR;   // lane's first global row
    const int pc0 = cb + cg * PC;   // lane's first global col

    const float k1 = pk1[0];
    const float k2 = pk2[0];
    const float a1 = pa1[0];
    const float a2 = pa2[0];
    const float inv12 = 1.0f / (k1 + k2);

    // Per-lane, per-patch-column material constants (col may straddle 256).
    float ckA[PC], ckD[PC], ckR[PC];
    #pragma unroll
    for (int c = 0; c < PC; ++c) {
        const int gc = pc0 + c;
        const float kap = (gc < 256) ? k1 : k2;
        const float alp = (gc < 256) ? a1 : a2;
        ckA[c] = kap * kCadv;
        ckD[c] = alp * kCdiff;
        ckR[c] = kCrea * kap;
    }

    // Shuffle source lanes (wrap is harmless: wrapped values feed only
    // halo-dirty cells and are finite).
    const int laneL = (lane + 63) & 63;
    const int laneR = (lane + 1) & 63;
    const int laneU = (lane + 56) & 63;
    const int laneD = (lane + 8) & 63;

    // Wave-uniform roles.
    const bool interior = (bx > 0 && bx < 31 && by > 0 && by < 31);
    const bool hasIface = (bx == 15 || bx == 16); // held cols cover 255
    const bool fTop = (by == 0), fBot = (by == 31);
    const bool fL = (bx == 0), fR = (bx == 31);
    const bool storeLane = (rg >= 2 && rg <= 5 && cg >= 2 && cg <= 5);

    // Initial load of the lane's 4x4 patch.
    float cur[PR][PC];
    if (interior) {
        #pragma unroll
        for (int r = 0; r < PR; ++r) {
            const float4 v = *reinterpret_cast<const float4*>(
                src + (pr0 + r) * GN + pc0);
            cur[r][0] = v.x; cur[r][1] = v.y; cur[r][2] = v.z; cur[r][3] = v.w;
        }
    } else {
        #pragma unroll
        for (int r = 0; r < PR; ++r) {
            const int gr = min(max(pr0 + r, 0), GN - 1);
            #pragma unroll
            for (int c = 0; c < PC; ++c) {
                const int gc = min(max(pc0 + c, 0), GN - 1);
                cur[r][c] = src[gr * GN + gc];
            }
        }
    }

    for (int s = 0; s < nsteps; ++s) {
        // Patch-edge exchange: 16 shfls, no LDS, no barrier.
        float tlE[PR], trE[PR], tmE[PC], tpE[PC];
        #pragma unroll
        for (int r = 0; r < PR; ++r) tlE[r] = __shfl(cur[r][PC - 1], laneL);
        #pragma unroll
        for (int r = 0; r < PR; ++r) trE[r] = __shfl(cur[r][0], laneR);
        #pragma unroll
        for (int c = 0; c < PC; ++c) tmE[c] = __shfl(cur[PR - 1][c], laneU);
        #pragma unroll
        for (int c = 0; c < PC; ++c) tpE[c] = __shfl(cur[0][c], laneD);

        float nxt[PR][PC];
        #pragma unroll
        for (int r = 0; r < PR; ++r) {
            #pragma unroll
            for (int c = 0; c < PC; ++c) {
                const float tc = cur[r][c];
                const float tm = (r > 0)      ? cur[r - 1][c] : tmE[c];
                const float tp = (r < PR - 1) ? cur[r + 1][c] : tpE[c];
                const float tl = (c > 0)      ? cur[r][c - 1] : tlE[r];
                const float tr = (c < PC - 1) ? cur[r][c + 1] : trE[r];
                const float t2 = tc * tc;
                const float adv = ckA[c] * (t2 * (tp - tm) - tc * (tr - tl));
                const float dif = ckD[c] * ((tm + tp + tl + tr) - 4.0f * tc);
                const float rea = ckR[c] * ((t2 * tc - t2) + tc);
                float v = tc - adv + dif + rea;
                if (hasIface) {
                    // interface col 255 (old-state rule), uniform branch
                    const float vif = (k1 * tr + k2 * tl) * inv12;
                    v = (pc0 + c == 255) ? vif : v;
                }
                nxt[r][c] = v;
            }
        }

        // Boundary fixes (intra-lane register copies; rows before cols).
        // by==0: global row 0 = local row 8 = (rg=2, pr=0) <- (rg=2, pr=1)
        if (fTop && rg == 2) {
            #pragma unroll
            for (int c = 0; c < PC; ++c) nxt[0][c] = nxt[1][c];
        }
        // by==31: global row 511 = local 23 = (rg=5, pr=3) <- (rg=5, pr=2)
        if (fBot && rg == 5) {
            #pragma unroll
            for (int c = 0; c < PC; ++c) nxt[3][c] = nxt[2][c];
        }
        // bx==0: global col 0 = local col 8 = (cg=2, pc=0) <- (cg=2, pc=1)
        if (fL && cg == 2) {
            #pragma unroll
            for (int r = 0; r < PR; ++r) nxt[r][0] = nxt[r][1];
        }
        // bx==31: global col 511 = local 23 = (cg=5, pc=3) <- (cg=5, pc=2)
        if (fR && cg == 5) {
            #pragma unroll
            for (int r = 0; r < PR; ++r) nxt[r][3] = nxt[r][2];
        }

        // Store owned 16x16 region (lanes rg,cg in [2,5]; full 4x4 patch).
        float* __restrict__ dst = dstbase + (size_t)s * GNN;
        if (storeLane) {
            #pragma unroll
            for (int r = 0; r < PR; ++r) {
                float4 v;
                v.x = nxt[r][0]; v.y = nxt[r][1];
                v.z = nxt[r][2]; v.w = nxt[r][3];
                *reinterpret_cast<float4*>(dst + (pr0 + r) * GN + pc0) = v;
            }
        }

        #pragma unroll
        for (int r = 0; r < PR; ++r)
            #pragma unroll
            for (int c = 0; c < PC; ++c) cur[r][c] = nxt[r][c];
    }
}

extern "C" void kernel_launch(void* const* d_in, const int* in_sizes, int n_in,
                              void* d_out, int out_size, void* d_ws, size_t ws_size,
                              hipStream_t stream) {
    (void)in_sizes; (void)n_in; (void)out_size; (void)d_ws; (void)ws_size;

    const float* u0 = (const float*)d_in[0];
    const float* k1 = (const float*)d_in[1];
    const float* k2 = (const float*)d_in[2];
    const float* a1 = (const float*)d_in[3];
    const float* a2 = (const float*)d_in[4];
    float* out = (float*)d_out;

    const dim3 block(64);
    const dim3 grid((GN / TS) * (GN / TS));   // 32x32 = 1024 waves

    const float* src = u0;
    int step = 0;
    while (step < NSTEPS) {
        const int ns = (NSTEPS - step < KS) ? (NSTEPS - step) : KS;
        float* dstbase = out + (size_t)step * GNN;
        adr_fused<<<grid, block, 0, stream>>>(src, dstbase, ns, k1, k2, a1, a2);
        src = dstbase + (size_t)(ns - 1) * GNN;
        step += ns;
    }
}

// Round 5
// 371.059 us; speedup vs baseline: 1.5556x; 1.0559x over previous
//
#include <hip/hip_runtime.h>

// Problem constants (from reference):
//   N = 512, DX = 1/511, DT = 1e-7, NUM_STEPS = 200 -> 199 output states
//   MB = 256 (material boundary column), interface column ii = 255
#define GN 512
#define GNN (GN * GN)
#define NSTEPS 199

// Barrier-free register-resident temporal fusion (structure verified passing
// in the 392us round):
//   TS = 16 output tile, KS = 8 fused steps, HS = 32 held tile.
//   ONE WAVE owns a held tile: lane grid 8x8, each lane a 4x4 patch in regs.
//   This round: horizontal exchange via DPP (wave_shr:1 / wave_shl:1) instead
//   of ds_bpermute; vertical bpermutes software-pipelined across steps
//   (issued right after boundary fixes, consumed next step after stores+DPP
//   overlap); ping-pong A<->B via unrolled macro (no reg copies); fma math.
#define TS 16
#define KS 8
#define PR 4
#define PC 4

// Precomputed coefficients (double -> float once):
__constant__ const float kCdiff = (float)(1e-7 * 511.0 * 511.0); // DT/DX^2
__constant__ const float kCadv  = (float)(1e-7 * 511.0 / 2.0);   // DT/(2DX)
__constant__ const float kCrea  = 1e-7f;                          // DT

// DPP lane+-1 exchange (CDNA keeps gfx9 wave_shl/shr DPP):
//   0x138 = wave_shr:1 (lane i <- lane i-1), 0x130 = wave_shl:1 (i <- i+1).
//   bound_ctrl=true: edge lanes read 0 — feeds only halo-dirty cells (finite).
#define DPP_SHR1(x) __int_as_float(__builtin_amdgcn_mov_dpp( \
    __float_as_int(x), 0x138, 0xf, 0xf, true))
#define DPP_SHL1(x) __int_as_float(__builtin_amdgcn_mov_dpp( \
    __float_as_int(x), 0x130, 0xf, 0xf, true))
#define BPERM(a, x) __int_as_float(__builtin_amdgcn_ds_bpermute( \
    (a), __float_as_int(x)))

// One fused step SRC->DST. TMI/TPI: incoming vertical edges (pipelined from
// previous step). TMO/TPO: outgoing edges for the next step, issued before
// stores so bpermute latency hides under VMEM + next step's interior rows.
// Row order {1,2,0,3}: edge rows (which consume TMI/TPI) computed last.
#define DO_STEP(SRC, DST, TMI, TPI, TMO, TPO, SIDX)                           \
{                                                                             \
    float tlE[PR], trE[PR];                                                   \
    _Pragma("unroll") for (int r = 0; r < PR; ++r) {                          \
        tlE[r] = DPP_SHR1(SRC[r][PC - 1]);                                    \
        trE[r] = DPP_SHL1(SRC[r][0]);                                         \
    }                                                                         \
    _Pragma("unroll") for (int ri = 0; ri < PR; ++ri) {                       \
        const int r = (ri == 0) ? 1 : (ri == 1) ? 2 : (ri == 2) ? 0 : 3;      \
        _Pragma("unroll") for (int c = 0; c < PC; ++c) {                      \
            const float tc = SRC[r][c];                                       \
            const float tm = (r > 0)      ? SRC[r - 1][c] : TMI[c];           \
            const float tp = (r < PR - 1) ? SRC[r + 1][c] : TPI[c];           \
            const float tl = (c > 0)      ? SRC[r][c - 1] : tlE[r];           \
            const float tr = (c < PC - 1) ? SRC[r][c + 1] : trE[r];           \
            const float t2 = tc * tc;                                         \
            const float dv = tp - tm;                                         \
            const float dh = tr - tl;                                         \
            const float lap = __builtin_fmaf(-4.0f, tc, (tm + tp) + (tl + tr)); \
            const float advt = __builtin_fmaf(t2, dv, -(tc * dh));            \
            const float reat = __builtin_fmaf(t2, tc - 1.0f, tc);             \
            float v = __builtin_fmaf(nckA[c], advt, tc);                      \
            v = __builtin_fmaf(ckD[c], lap, v);                               \
            v = __builtin_fmaf(ckR[c], reat, v);                              \
            if (hasIface) {                                                   \
                const float vif = __builtin_fmaf(k1, tr, k2 * tl) * inv12;    \
                v = (pc0 + c == 255) ? vif : v;                               \
            }                                                                 \
            DST[r][c] = v;                                                    \
        }                                                                     \
    }                                                                         \
    /* boundary fixes (rows before cols, matching reference order) */         \
    if (fTop && rg == 2) { _Pragma("unroll")                                  \
        for (int c = 0; c < PC; ++c) DST[0][c] = DST[1][c]; }                 \
    if (fBot && rg == 5) { _Pragma("unroll")                                  \
        for (int c = 0; c < PC; ++c) DST[PR - 1][c] = DST[PR - 2][c]; }       \
    if (fL && cg == 2) { _Pragma("unroll")                                    \
        for (int r = 0; r < PR; ++r) DST[r][0] = DST[r][1]; }                 \
    if (fR && cg == 5) { _Pragma("unroll")                                    \
        for (int r = 0; r < PR; ++r) DST[r][PC - 1] = DST[r][PC - 2]; }       \
    /* issue next step's vertical exchange early (post-fix values) */         \
    _Pragma("unroll") for (int c = 0; c < PC; ++c) {                          \
        TMO[c] = BPERM(aU, DST[PR - 1][c]);                                   \
        TPO[c] = BPERM(aD, DST[0][c]);                                        \
    }                                                                         \
    if (storeLane) {                                                          \
        float* __restrict__ dsts = dstbase + (size_t)(SIDX) * GNN + lofs;     \
        _Pragma("unroll") for (int r = 0; r < PR; ++r) {                      \
            float4 v4;                                                        \
            v4.x = DST[r][0]; v4.y = DST[r][1];                               \
            v4.z = DST[r][2]; v4.w = DST[r][3];                               \
            *reinterpret_cast<float4*>(dsts + r * GN) = v4;                   \
        }                                                                     \
    }                                                                         \
}

__global__ __launch_bounds__(64) void adr_fused(
    const float* __restrict__ src, float* __restrict__ dstbase, int nsteps,
    const float* __restrict__ pk1, const float* __restrict__ pk2,
    const float* __restrict__ pa1, const float* __restrict__ pa2)
{
    const int lane = threadIdx.x & 63;
    const int cg = lane & 7;        // col group
    const int rg = lane >> 3;       // row group
    const int bx = blockIdx.x & 31; // tile col
    const int by = blockIdx.x >> 5; // tile row
    const int rb = by * TS - KS;    // held-region base row (may be <0)
    const int cb = bx * TS - KS;    // held-region base col
    const int pr0 = rb + rg * PR;   // lane's first global row
    const int pc0 = cb + cg * PC;   // lane's first global col
    const int lofs = pr0 * GN + pc0;

    const float k1 = pk1[0];
    const float k2 = pk2[0];
    const float a1 = pa1[0];
    const float a2 = pa2[0];
    const float inv12 = 1.0f / (k1 + k2);

    // Per-lane per-patch-column material constants (negated adv coeff so the
    // combine is a pure fma chain).
    float nckA[PC], ckD[PC], ckR[PC];
    #pragma unroll
    for (int c = 0; c < PC; ++c) {
        const int gc = pc0 + c;
        const float kap = (gc < 256) ? k1 : k2;
        const float alp = (gc < 256) ? a1 : a2;
        nckA[c] = -(kap * kCadv);
        ckD[c]  = alp * kCdiff;
        ckR[c]  = kCrea * kap;
    }

    // Vertical bpermute byte addresses (wrap feeds only halo-dirty cells).
    const int aU = ((lane + 56) & 63) << 2;
    const int aD = ((lane + 8) & 63) << 2;

    // Wave-uniform roles.
    const bool interior = (bx > 0 && bx < 31 && by > 0 && by < 31);
    const bool hasIface = (bx == 15 || bx == 16);
    const bool fTop = (by == 0), fBot = (by == 31);
    const bool fL = (bx == 0), fR = (bx == 31);
    const bool storeLane = (rg >= 2 && rg <= 5 && cg >= 2 && cg <= 5);

    // Initial load of the lane's 4x4 patch.
    float A[PR][PC], B[PR][PC];
    if (interior) {
        #pragma unroll
        for (int r = 0; r < PR; ++r) {
            const float4 v = *reinterpret_cast<const float4*>(
                src + (pr0 + r) * GN + pc0);
            A[r][0] = v.x; A[r][1] = v.y; A[r][2] = v.z; A[r][3] = v.w;
        }
    } else {
        #pragma unroll
        for (int r = 0; r < PR; ++r) {
            const int gr = min(max(pr0 + r, 0), GN - 1);
            #pragma unroll
            for (int c = 0; c < PC; ++c) {
                const int gc = min(max(pc0 + c, 0), GN - 1);
                A[r][c] = src[gr * GN + gc];
            }
        }
    }

    // Pre-issue step 0's vertical exchange.
    float tm0[PC], tp0[PC], tm1[PC], tp1[PC];
    #pragma unroll
    for (int c = 0; c < PC; ++c) {
        tm0[c] = BPERM(aU, A[PR - 1][c]);
        tp0[c] = BPERM(aD, A[0][c]);
    }

    // Ping-pong step loop, fully unrolled (nsteps <= KS; uniform breaks).
    #pragma unroll
    for (int s = 0; s < KS; s += 2) {
        if (s >= nsteps) break;
        DO_STEP(A, B, tm0, tp0, tm1, tp1, s)
        if (s + 1 >= nsteps) break;
        DO_STEP(B, A, tm1, tp1, tm0, tp0, s + 1)
    }
}

extern "C" void kernel_launch(void* const* d_in, const int* in_sizes, int n_in,
                              void* d_out, int out_size, void* d_ws, size_t ws_size,
                              hipStream_t stream) {
    (void)in_sizes; (void)n_in; (void)out_size; (void)d_ws; (void)ws_size;

    const float* u0 = (const float*)d_in[0];
    const float* k1 = (const float*)d_in[1];
    const float* k2 = (const float*)d_in[2];
    const float* a1 = (const float*)d_in[3];
    const float* a2 = (const float*)d_in[4];
    float* out = (float*)d_out;

    const dim3 block(64);
    const dim3 grid((GN / TS) * (GN / TS));   // 32x32 = 1024 waves, 1/SIMD

    const float* src = u0;
    int step = 0;
    while (step < NSTEPS) {
        const int ns = (NSTEPS - step < KS) ? (NSTEPS - step) : KS;
        float* dstbase = out + (size_t)step * GNN;
        adr_fused<<<grid, block, 0, stream>>>(src, dstbase, ns, k1, k2, a1, a2);
        src = dstbase + (size_t)(ns - 1) * GNN;
        step += ns;
    }
}